// Round 4
// baseline (494.018 us; speedup 1.0000x reference)
//
#include <hip/hip_runtime.h>
#include <hip/hip_bf16.h>

typedef unsigned short u16;
typedef unsigned short u16x8 __attribute__((ext_vector_type(8)));
typedef __bf16 bf16x8 __attribute__((ext_vector_type(8)));
typedef float f32x4 __attribute__((ext_vector_type(4)));

#define LRS 0.2f

__device__ __forceinline__ u16 f2b(float f) {
  __hip_bfloat16 h = __float2bfloat16(f);
  return __builtin_bit_cast(u16, h);
}

// ---------------------------------------------------------------------------
// Generic: 4 rows (staged in LDS f32, rows at stride K) x W[O][K] f32 -> y[4][O]
// ---------------------------------------------------------------------------
template<int K, int O, int KSEG>
__device__ __forceinline__ void gemm_rows4(const float* xr, const float* W, const float* bias,
                                           float* yl, float* yg, int ygstride) {
  constexpr int KPT = K / KSEG;
  constexpr int OPP = 256 / KSEG;
  const int t = threadIdx.x;
  const int ks = t % KSEG;
  const int oi = t / KSEG;
#pragma unroll
  for (int pass = 0; pass < O / OPP; ++pass) {
    const int o = pass * OPP + oi;
    float a0 = 0, a1 = 0, a2 = 0, a3 = 0;
    const float* wp = W + (size_t)o * K + ks * KPT;
    const float* xb = xr + ks * KPT;
#pragma unroll 4
    for (int kc = 0; kc < KPT; kc += 4) {
      f32x4 w4 = *(const f32x4*)(wp + kc);
      const float* xp = xb + kc;
#pragma unroll
      for (int j = 0; j < 4; ++j) {
        float w = w4[j];
        a0 += xp[j] * w;
        a1 += xp[K + j] * w;
        a2 += xp[2 * K + j] * w;
        a3 += xp[3 * K + j] * w;
      }
    }
#pragma unroll
    for (int d = 1; d < KSEG; d <<= 1) {
      a0 += __shfl_xor(a0, d, 64);
      a1 += __shfl_xor(a1, d, 64);
      a2 += __shfl_xor(a2, d, 64);
      a3 += __shfl_xor(a3, d, 64);
    }
    if (ks == 0) {
      float bv = bias ? bias[o] : 0.0f;
      float v0 = a0 + bv, v1 = a1 + bv, v2 = a2 + bv, v3 = a3 + bv;
      if (yl) { yl[o] = v0; yl[O + o] = v1; yl[2 * O + o] = v2; yl[3 * O + o] = v3; }
      if (yg) { yg[o] = v0; yg[ygstride + o] = v1; yg[2 * (size_t)ygstride + o] = v2; yg[3 * (size_t)ygstride + o] = v3; }
    }
  }
}

// ---------------------------------------------------------------------------
// W1: fold weights. Mfull[hf][c], vf[c][h] f32 (score vectors), cbe, sconst
// ---------------------------------------------------------------------------
__global__ __launch_bounds__(256) void kW1(const float* We_w, const float* We_b, const float* attn,
                                           const float* We2_w, const float* We2_b,
                                           const float* edge_w, const float* edge_b,
                                           float* Mfull, float* vf, float* cbe, float* sconst) {
  int gid = blockIdx.x * 256 + threadIdx.x;
  if (gid < 16384) {
    int hf = gid >> 7, c = gid & 127;
    int h = hf >> 4, fo = hf & 15;
    float s = 0;
    for (int e = 0; e < 16; ++e)
      s += edge_w[fo * 176 + e] * We2_w[(h * 16 + e) * 128 + c];
    Mfull[hf * 128 + c] = s;
  } else if (gid < 16384 + 2048) {
    int idx = gid - 16384;
    int c = idx >> 4, hc = idx & 15;
    if (hc < 8) {
      float s = 0;
      for (int e = 0; e < 16; ++e)
        s += We_w[(hc * 16 + e) * 128 + c] * attn[128 + e];
      vf[c * 8 + hc] = s;
    }
  } else if (gid < 18432 + 128) {
    int hf = gid - 18432;
    int h = hf >> 4, fo = hf & 15;
    float s = edge_b[fo];
    for (int e = 0; e < 16; ++e)
      s += We2_b[h * 16 + e] * edge_w[fo * 176 + e];
    cbe[hf] = s;
  } else if (gid < 18560 + 8) {
    int h = gid - 18560;
    float s = 0;
    for (int e = 0; e < 16; ++e)
      s += We_b[h * 16 + e] * attn[128 + e];
    sconst[h] = s;
  }
}

// W2: G[o][c] = sum_k oute_w[o,k]*Mfull[k][c], stored bf16 row-major (o,c)
__global__ __launch_bounds__(256) void kW2(const float* oute_w, const float* Mfull, u16* Gb) {
  int gid = blockIdx.x * 256 + threadIdx.x;
  int o = gid >> 7, c = gid & 127;
  float s = 0;
  for (int k = 0; k < 128; ++k)
    s += oute_w[o * 128 + k] * Mfull[k * 128 + c];
  Gb[o * 128 + c] = f2b(s);
}

// ---------------------------------------------------------------------------
// N1: per 4 node-rows: npj, dpj, node_wh, srow, scol
// ---------------------------------------------------------------------------
__global__ __launch_bounds__(256) void kN1(const float* node, const float* diff,
                                           const float* Wn_w, const float* Wn_b,
                                           const float* Wd_w, const float* Wd_b,
                                           const float* Wh_w, const float* Wh_b,
                                           const float* attn, const float* sconst,
                                           float* npj_g, float* nwh_g,
                                           float* srow_g, float* scol_g) {
  __shared__ float nrow[4 * 512], npjl[4 * 512], drow[4 * 128], dpjl[4 * 128];
  const int t = threadIdx.x;
  const int r0 = blockIdx.x * 4;
  *(f32x4*)&nrow[t * 8]     = *(const f32x4*)(node + (size_t)r0 * 512 + t * 8);
  *(f32x4*)&nrow[t * 8 + 4] = *(const f32x4*)(node + (size_t)r0 * 512 + t * 8 + 4);
  if (t < 64) {
    *(f32x4*)&drow[t * 8]     = *(const f32x4*)(diff + (size_t)r0 * 128 + t * 8);
    *(f32x4*)&drow[t * 8 + 4] = *(const f32x4*)(diff + (size_t)r0 * 128 + t * 8 + 4);
  }
  __syncthreads();
  gemm_rows4<512, 512, 4>(nrow, Wn_w, Wn_b, npjl, npj_g + (size_t)r0 * 512, 512);
  gemm_rows4<128, 128, 4>(drow, Wd_w, Wd_b, dpjl, nullptr, 0);
  __syncthreads();
  {
    int d = t & 63, hh = t >> 6;
#pragma unroll
    for (int hi = 0; hi < 2; ++hi) {
      int h = hh + hi * 4;
      float wb = Wh_b[d];
      float acc[4] = {wb, wb, wb, wb};
      for (int k = 0; k < 64; ++k) {
        float w = Wh_w[d * 64 + k];
#pragma unroll
        for (int r = 0; r < 4; ++r) acc[r] += npjl[r * 512 + h * 64 + k] * w;
      }
#pragma unroll
      for (int r = 0; r < 4; ++r) nwh_g[(size_t)(r0 + r) * 512 + h * 64 + d] = acc[r];
    }
  }
  if (t < 32) {
    int r = t >> 3, h = t & 7;
    float shi = 0, shj = 0, sdi = 0, sdj = 0;
    for (int d = 0; d < 64; ++d) {
      float x = npjl[r * 512 + h * 64 + d];
      shi += x * attn[d];
      shj += x * attn[64 + d];
    }
    for (int e = 0; e < 16; ++e) {
      float x = dpjl[r * 128 + h * 16 + e];
      sdi += x * attn[144 + e];
      sdj += x * attn[160 + e];
    }
    srow_g[(r0 + r) * 8 + h] = shi + sdi + sconst[h];
    scol_g[(r0 + r) * 8 + h] = shj + sdj;
  }
}

// ---------------------------------------------------------------------------
// A: per (b,l): scores via coalesced VALU row-dots, softmax, agg, new_node_pre
// ---------------------------------------------------------------------------
__global__ __launch_bounds__(256) void kA(const float* edge, const float* npj, const float* nwh,
                                          const float* srow, const float* scol,
                                          const float* vf, float* nnp) {
  __shared__ float s_arr[512][9];
  __shared__ float red[256];
  __shared__ float mxh[8], inv8[8];
  __shared__ float part[2][512];
  const int bl = blockIdx.x;
  const int b = bl >> 9, l = bl & 511;
  const int t = threadIdx.x;

  // ---- phase S: se[m][h] = edge[bl,m,:]·v[:,h]  (f32, coalesced) ----
  {
    const int sub = t & 15, rg = t >> 4;
    f32x4 vrx[16];
#pragma unroll
    for (int q = 0; q < 16; ++q) vrx[q] = *(const f32x4*)(vf + sub * 64 + q * 4);
    const float* ebase = edge + (size_t)bl * 65536 + (size_t)rg * 128 + sub * 8;
    f32x4 c0 = *(const f32x4*)ebase;
    f32x4 c1 = *(const f32x4*)(ebase + 4);
    for (int it = 0; it < 32; ++it) {
      f32x4 n0, n1;
      if (it < 31) {
        const float* ep = ebase + (size_t)(it + 1) * 2048;
        n0 = *(const f32x4*)ep;
        n1 = *(const f32x4*)(ep + 4);
      }
      float acc[8];
#pragma unroll
      for (int h2 = 0; h2 < 8; ++h2) acc[h2] = 0.0f;
#pragma unroll
      for (int j = 0; j < 4; ++j) {
#pragma unroll
        for (int h2 = 0; h2 < 8; ++h2) {
          acc[h2] += c0[j] * vrx[j * 2 + (h2 >> 2)][h2 & 3];
          acc[h2] += c1[j] * vrx[8 + j * 2 + (h2 >> 2)][h2 & 3];
        }
      }
#pragma unroll
      for (int d = 1; d < 16; d <<= 1) {
#pragma unroll
        for (int h2 = 0; h2 < 8; ++h2) acc[h2] += __shfl_xor(acc[h2], d, 64);
      }
      if (sub < 8) {
        float a = acc[0];
#pragma unroll
        for (int h2 = 1; h2 < 8; ++h2) if (sub == h2) a = acc[h2];
        s_arr[it * 16 + rg][sub] = a;
      }
      if (it < 31) { c0 = n0; c1 = n1; }
    }
  }
  __syncthreads();

  // ---- softmax: add biases, lrelu, diag; max ----
  const int h = t & 7, seg = t >> 3;
  const float srh2 = srow[(size_t)bl * 8 + h];
  float mx = -__builtin_inff();
#pragma unroll 4
  for (int i = 0; i < 16; ++i) {
    int m = seg * 16 + i;
    float sv = s_arr[m][h] + srh2 + scol[((size_t)b * 512 + m) * 8 + h];
    sv = (m == l) ? -__builtin_inff() : (sv >= 0.0f ? sv : LRS * sv);
    s_arr[m][h] = sv;
    mx = fmaxf(mx, sv);
  }
  red[t] = mx;
  __syncthreads();
  if (t < 8) {
    float m2 = -__builtin_inff();
    for (int sg = 0; sg < 32; ++sg) m2 = fmaxf(m2, red[sg * 8 + t]);
    mxh[t] = m2;
  }
  __syncthreads();
  float mh = mxh[h];
  float sm = 0;
#pragma unroll 4
  for (int i = 0; i < 16; ++i) {
    int m = seg * 16 + i;
    float p = __expf(s_arr[m][h] - mh);
    s_arr[m][h] = p;
    sm += p;
  }
  red[t] = sm;
  __syncthreads();
  if (t < 8) {
    float s2 = 0;
    for (int sg = 0; sg < 32; ++sg) s2 += red[sg * 8 + t];
    inv8[t] = 1.0f / s2;
  }
  __syncthreads();

  // ---- agg[o] = sum_m p[m][h]*node_wh[b,m,o] ----
  const int half = t >> 7, oq = t & 127;
  const int o4 = oq * 4, hh = oq >> 4;
  f32x4 acc4a = {0, 0, 0, 0}, acc4b = {0, 0, 0, 0};
  const float* nb = nwh + (size_t)b * 512 * 512;
  for (int m = half * 256; m < half * 256 + 256; m += 2) {
    acc4a += s_arr[m][hh]     * *(const f32x4*)(nb + (size_t)m * 512 + o4);
    acc4b += s_arr[m + 1][hh] * *(const f32x4*)(nb + (size_t)(m + 1) * 512 + o4);
  }
  *(f32x4*)&part[half][o4] = acc4a + acc4b;
  __syncthreads();
  if (t < 128) {
    int ob = t * 4, h2 = t >> 4;
    f32x4 s0 = *(f32x4*)&part[0][ob];
    f32x4 s1 = *(f32x4*)&part[1][ob];
    f32x4 np4 = *(const f32x4*)(npj + (size_t)bl * 512 + ob);
    float iv = inv8[h2];
    f32x4 o;
#pragma unroll
    for (int j = 0; j < 4; ++j) {
      float a = (s0[j] + s1[j]) * iv;
      a = a >= 0.0f ? a : LRS * a;
      o[j] = np4[j] + a;
    }
    *(f32x4*)(nnp + (size_t)bl * 512 + ob) = o;
  }
}

// N2: new_node = nnp @ outn^T + b  -> f32 out (also serves as stage-2 input)
__global__ __launch_bounds__(256) void kN2(const float* nnp, const float* outn_w, const float* outn_b,
                                           float* out0) {
  __shared__ float xr[4 * 512];
  const int t = threadIdx.x;
  const int r0 = blockIdx.x * 4;
  *(f32x4*)&xr[t * 4]        = *(const f32x4*)(nnp + (size_t)r0 * 512 + t * 4);
  *(f32x4*)&xr[1024 + t * 4] = *(const f32x4*)(nnp + (size_t)r0 * 512 + 1024 + t * 4);
  __syncthreads();
  gemm_rows4<512, 512, 4>(xr, outn_w, outn_b, nullptr, out0 + (size_t)r0 * 512, 512);
}

// N3: np2, dp2, then Rl/Rm (with cbe folded into Rl)
__global__ __launch_bounds__(256) void kN3(const float* nn, const float* diff,
                                           const float* Wn2_w, const float* Wn2_b,
                                           const float* Wd2_w, const float* Wd2_b,
                                           const float* edge_w, const float* cbe,
                                           float* Rl_g, float* Rm_g) {
  __shared__ float xr[4 * 512], np2l[4 * 512], dr[4 * 128], dp2l[4 * 128];
  const int t = threadIdx.x;
  const int r0 = blockIdx.x * 4;
  *(f32x4*)&xr[t * 4]        = *(const f32x4*)(nn + (size_t)r0 * 512 + t * 4);
  *(f32x4*)&xr[1024 + t * 4] = *(const f32x4*)(nn + (size_t)r0 * 512 + 1024 + t * 4);
  if (t < 64) {
    *(f32x4*)&dr[t * 8]     = *(const f32x4*)(diff + (size_t)r0 * 128 + t * 8);
    *(f32x4*)&dr[t * 8 + 4] = *(const f32x4*)(diff + (size_t)r0 * 128 + t * 8 + 4);
  }
  __syncthreads();
  gemm_rows4<512, 512, 4>(xr, Wn2_w, Wn2_b, np2l, nullptr, 0);
  gemm_rows4<128, 128, 4>(dr, Wd2_w, Wd2_b, dp2l, nullptr, 0);
  __syncthreads();
  {
    int hf = t & 127, which = t >> 7;
    int h = hf >> 4, fo = hf & 15;
    const float* wh = edge_w + fo * 176 + 16 + which * 64;   // W_hi / W_hj
    const float* wd = edge_w + fo * 176 + 144 + which * 16;  // W_di / W_dj
    float add = which ? 0.0f : cbe[hf];
    float* dst = which ? Rm_g : Rl_g;
#pragma unroll
    for (int r = 0; r < 4; ++r) {
      float a = add;
      for (int d = 0; d < 64; ++d) a += np2l[r * 512 + h * 64 + d] * wh[d];
      for (int e = 0; e < 16; ++e) a += dp2l[r * 128 + h * 16 + e] * wd[e];
      dst[(size_t)(r0 + r) * 128 + hf] = a;
    }
  }
}

// N4: Pl = Rl@oute^T + oute_b ; Pm = Rm@oute^T
__global__ __launch_bounds__(256) void kN4(const float* Rl, const float* Rm,
                                           const float* oute_w, const float* oute_b,
                                           float* Pl, float* Pm) {
  __shared__ float xl[4 * 128], xm[4 * 128];
  const int t = threadIdx.x;
  const int r0 = blockIdx.x * 4;
  if (t < 128) *(f32x4*)&xl[t * 4] = *(const f32x4*)(Rl + (size_t)r0 * 128 + t * 4);
  else { int q = t - 128; *(f32x4*)&xm[q * 4] = *(const f32x4*)(Rm + (size_t)r0 * 128 + q * 4); }
  __syncthreads();
  gemm_rows4<128, 128, 4>(xl, oute_w, oute_b, nullptr, Pl + (size_t)r0 * 128, 128);
  gemm_rows4<128, 128, 4>(xm, oute_w, nullptr, nullptr, Pm + (size_t)r0 * 128, 128);
}

// ---------------------------------------------------------------------------
// E: per bl: new_edge[bl,m,:] = edge@G^T + Pl[bl] + Pm[b,m]
// 8 sub-tiles of 64 rows, double-buffered LDS + register prefetch.
// ---------------------------------------------------------------------------
__global__ __launch_bounds__(256) void kE(const float* edge, const u16* Gb,
                                          const float* Pl, const float* Pm, float* oute) {
  __shared__ u16 Gt[16384];
  __shared__ u16 At[2][8192];
  const int bl = blockIdx.x;
  const int b = bl >> 9;
  const int t = threadIdx.x, lane = t & 63, w = t >> 6;
  const float* Ab = edge + (size_t)bl * 65536;
  const int arow = t >> 2, aseg = t & 3;

  f32x4 pf[8];
  auto issueA = [&](int tile) {
    const float* p = Ab + (size_t)(tile * 64 + arow) * 128 + aseg * 32;
#pragma unroll
    for (int q = 0; q < 8; ++q) pf[q] = *(const f32x4*)(p + q * 4);
  };
  auto writeA = [&](int buf) {
#pragma unroll
    for (int jj = 0; jj < 4; ++jj) {
      u16x8 a8;
#pragma unroll
      for (int j2 = 0; j2 < 4; ++j2) {
        a8[j2]     = f2b(pf[2 * jj][j2]);
        a8[4 + j2] = f2b(pf[2 * jj + 1][j2]);
      }
      int cu = aseg * 4 + jj;
      *(u16x8*)(At[buf] + (arow * 16 + (cu ^ (arow & 7))) * 8) = a8;
    }
  };

  issueA(0);
#pragma unroll
  for (int i2 = 0; i2 < 8; ++i2) {
    int u = i2 * 256 + t;
    int row = u >> 4, cu = u & 15;
    *(u16x8*)(Gt + (row * 16 + (cu ^ (row & 7))) * 8) = *(const u16x8*)(Gb + u * 8);
  }
  writeA(0);
  __syncthreads();

  const int wr = w >> 1, wc = w & 1;
  const int colL = lane & 15, kg = lane >> 4;
  const float* plp = Pl + (size_t)bl * 128;
  float plv[4];
#pragma unroll
  for (int n = 0; n < 4; ++n) plv[n] = plp[wc * 64 + n * 16 + colL];

  for (int tile = 0; tile < 8; ++tile) {
    if (tile < 7) issueA(tile + 1);
    const int buf = tile & 1;
    f32x4 acc[2][4] = {};
#pragma unroll
    for (int ks = 0; ks < 4; ++ks) {
      int cu = ks * 4 + kg;
      bf16x8 af[2], bfv[4];
#pragma unroll
      for (int i = 0; i < 2; ++i) {
        int row = wr * 32 + i * 16 + colL;
        af[i] = *(bf16x8*)(At[buf] + (row * 16 + (cu ^ (row & 7))) * 8);
      }
#pragma unroll
      for (int n = 0; n < 4; ++n) {
        int orow = wc * 64 + n * 16 + colL;
        bfv[n] = *(bf16x8*)(Gt + (orow * 16 + (cu ^ (orow & 7))) * 8);
      }
#pragma unroll
      for (int i = 0; i < 2; ++i)
#pragma unroll
        for (int n = 0; n < 4; ++n)
          acc[i][n] = __builtin_amdgcn_mfma_f32_16x16x32_bf16(af[i], bfv[n], acc[i][n], 0, 0, 0);
    }
    if (tile < 7) writeA(buf ^ 1);
    // epilogue: add Pl+Pm, store
    const int m0 = tile * 64;
    float* ob = oute + ((size_t)bl * 512 + m0) * 128;
#pragma unroll
    for (int i = 0; i < 2; ++i) {
#pragma unroll
      for (int r = 0; r < 4; ++r) {
        int m = wr * 32 + i * 16 + kg * 4 + r;
        const float* pmp = Pm + ((size_t)b * 512 + m0 + m) * 128;
#pragma unroll
        for (int n = 0; n < 4; ++n) {
          int o = wc * 64 + n * 16 + colL;
          ob[(size_t)m * 128 + o] = acc[i][n][r] + plv[n] + pmp[o];
        }
      }
    }
    __syncthreads();
  }
}

extern "C" void kernel_launch(void* const* d_in, const int* in_sizes, int n_in,
                              void* d_out, int out_size, void* d_ws, size_t ws_size,
                              hipStream_t stream) {
  (void)in_sizes; (void)n_in; (void)out_size; (void)ws_size;
  const float* node   = (const float*)d_in[0];
  const float* edge   = (const float*)d_in[1];
  const float* diff   = (const float*)d_in[2];
  const float* Wn_w   = (const float*)d_in[3];
  const float* Wn_b   = (const float*)d_in[4];
  const float* We_w   = (const float*)d_in[5];
  const float* We_b   = (const float*)d_in[6];
  const float* Wd_w   = (const float*)d_in[7];
  const float* Wd_b   = (const float*)d_in[8];
  const float* Wh_w   = (const float*)d_in[9];
  const float* Wh_b   = (const float*)d_in[10];
  const float* attn   = (const float*)d_in[11];
  const float* outn_w = (const float*)d_in[12];
  const float* outn_b = (const float*)d_in[13];
  const float* Wn2_w  = (const float*)d_in[14];
  const float* Wn2_b  = (const float*)d_in[15];
  const float* We2_w  = (const float*)d_in[16];
  const float* We2_b  = (const float*)d_in[17];
  const float* Wd2_w  = (const float*)d_in[18];
  const float* Wd2_b  = (const float*)d_in[19];
  const float* edge_w = (const float*)d_in[20];
  const float* edge_b = (const float*)d_in[21];
  const float* oute_w = (const float*)d_in[22];
  const float* oute_b = (const float*)d_in[23];

  float* out0 = (float*)d_out;           // new_node f32 (524288)
  float* out1 = out0 + 524288;           // new_edge f32

  float* f = (float*)d_ws;
  size_t off = 0;
  auto alloc = [&](size_t n) { float* p = f + off; off += (n + 7) & ~(size_t)7; return p; };
  float* npj    = alloc(524288);
  float* nwh    = alloc(524288);
  float* srow   = alloc(8192);
  float* scol   = alloc(8192);
  float* sconst = alloc(8);
  float* cbe    = alloc(128);
  float* Mfull  = alloc(16384);
  float* nnp    = alloc(524288);
  float* Rl     = alloc(131072);
  float* Rm     = alloc(131072);
  float* Pl     = alloc(131072);
  float* Pm     = alloc(131072);
  float* vf     = alloc(1024);
  u16* Gb = (u16*)(f + off); off += 8192;   // 16384 u16

  hipLaunchKernelGGL(kW1, dim3(73), dim3(256), 0, stream,
                     We_w, We_b, attn, We2_w, We2_b, edge_w, edge_b, Mfull, vf, cbe, sconst);
  hipLaunchKernelGGL(kW2, dim3(64), dim3(256), 0, stream, oute_w, Mfull, Gb);
  hipLaunchKernelGGL(kN1, dim3(256), dim3(256), 0, stream,
                     node, diff, Wn_w, Wn_b, Wd_w, Wd_b, Wh_w, Wh_b, attn, sconst,
                     npj, nwh, srow, scol);
  hipLaunchKernelGGL(kA, dim3(1024), dim3(256), 0, stream,
                     edge, npj, nwh, srow, scol, vf, nnp);
  hipLaunchKernelGGL(kN2, dim3(256), dim3(256), 0, stream, nnp, outn_w, outn_b, out0);
  hipLaunchKernelGGL(kN3, dim3(256), dim3(256), 0, stream,
                     out0, diff, Wn2_w, Wn2_b, Wd2_w, Wd2_b, edge_w, cbe, Rl, Rm);
  hipLaunchKernelGGL(kN4, dim3(256), dim3(256), 0, stream, Rl, Rm, oute_w, oute_b, Pl, Pm);
  hipLaunchKernelGGL(kE, dim3(1024), dim3(256), 0, stream, edge, Gb, Pl, Pm, out1);
}

// Round 5
// 472.694 us; speedup vs baseline: 1.0451x; 1.0451x over previous
//
#include <hip/hip_runtime.h>
#include <hip/hip_bf16.h>

typedef unsigned short u16;
typedef unsigned short u16x8 __attribute__((ext_vector_type(8)));
typedef __bf16 bf16x8 __attribute__((ext_vector_type(8)));
typedef float f32x4 __attribute__((ext_vector_type(4)));

#define LRS 0.2f

__device__ __forceinline__ float bf2f(u16 u) { return __uint_as_float(((unsigned)u) << 16); }
__device__ __forceinline__ u16 f2b(float f) {
  __hip_bfloat16 h = __float2bfloat16(f);
  return __builtin_bit_cast(u16, h);
}

// ---------------------------------------------------------------------------
// Generic: 4 rows (LDS f32, rows at stride K) x W[O][K] f32 -> y[4][O]
// Vector (b128) LDS reads; KSEG threads cooperate along K via shfl reduce.
// ---------------------------------------------------------------------------
template<int K, int O, int KSEG>
__device__ __forceinline__ void gemm_rows4(const float* xr, const float* W, const float* bias,
                                           float* yl, float* yg, int ygstride) {
  constexpr int KPT = K / KSEG;
  constexpr int OPP = 256 / KSEG;
  const int t = threadIdx.x;
  const int ks = t % KSEG;
  const int oi = t / KSEG;
#pragma unroll
  for (int pass = 0; pass < O / OPP; ++pass) {
    const int o = pass * OPP + oi;
    float a0 = 0, a1 = 0, a2 = 0, a3 = 0;
    const float* wp = W + (size_t)o * K + ks * KPT;
    const float* xb = xr + ks * KPT;
#pragma unroll 4
    for (int kc = 0; kc < KPT; kc += 4) {
      f32x4 w4 = *(const f32x4*)(wp + kc);
      f32x4 x0 = *(const f32x4*)(xb + kc);
      f32x4 x1 = *(const f32x4*)(xb + K + kc);
      f32x4 x2 = *(const f32x4*)(xb + 2 * K + kc);
      f32x4 x3 = *(const f32x4*)(xb + 3 * K + kc);
#pragma unroll
      for (int j = 0; j < 4; ++j) {
        float w = w4[j];
        a0 += x0[j] * w;
        a1 += x1[j] * w;
        a2 += x2[j] * w;
        a3 += x3[j] * w;
      }
    }
#pragma unroll
    for (int d = 1; d < KSEG; d <<= 1) {
      a0 += __shfl_xor(a0, d, 64);
      a1 += __shfl_xor(a1, d, 64);
      a2 += __shfl_xor(a2, d, 64);
      a3 += __shfl_xor(a3, d, 64);
    }
    if (ks == 0) {
      float bv = bias ? bias[o] : 0.0f;
      float v0 = a0 + bv, v1 = a1 + bv, v2 = a2 + bv, v3 = a3 + bv;
      if (yl) { yl[o] = v0; yl[O + o] = v1; yl[2 * O + o] = v2; yl[3 * O + o] = v3; }
      if (yg) { yg[o] = v0; yg[ygstride + o] = v1; yg[2 * (size_t)ygstride + o] = v2; yg[3 * (size_t)ygstride + o] = v3; }
    }
  }
}

// ---------------------------------------------------------------------------
// W1: fold weights. Mfull[hf][c], vf[c][h] f32 (score vectors), cbe, sconst
// ---------------------------------------------------------------------------
__global__ __launch_bounds__(256) void kW1(const float* We_w, const float* We_b, const float* attn,
                                           const float* We2_w, const float* We2_b,
                                           const float* edge_w, const float* edge_b,
                                           float* Mfull, float* vf, float* cbe, float* sconst) {
  int gid = blockIdx.x * 256 + threadIdx.x;
  if (gid < 16384) {
    int hf = gid >> 7, c = gid & 127;
    int h = hf >> 4, fo = hf & 15;
    float s = 0;
    for (int e = 0; e < 16; ++e)
      s += edge_w[fo * 176 + e] * We2_w[(h * 16 + e) * 128 + c];
    Mfull[hf * 128 + c] = s;
  } else if (gid < 16384 + 2048) {
    int idx = gid - 16384;
    int c = idx >> 4, hc = idx & 15;
    if (hc < 8) {
      float s = 0;
      for (int e = 0; e < 16; ++e)
        s += We_w[(hc * 16 + e) * 128 + c] * attn[128 + e];
      vf[c * 8 + hc] = s;
    }
  } else if (gid < 18432 + 128) {
    int hf = gid - 18432;
    int h = hf >> 4, fo = hf & 15;
    float s = edge_b[fo];
    for (int e = 0; e < 16; ++e)
      s += We2_b[h * 16 + e] * edge_w[fo * 176 + e];
    cbe[hf] = s;
  } else if (gid < 18560 + 8) {
    int h = gid - 18560;
    float s = 0;
    for (int e = 0; e < 16; ++e)
      s += We_b[h * 16 + e] * attn[128 + e];
    sconst[h] = s;
  }
}

// W2: G[o][c] = sum_k oute_w[o,k]*Mfull[k][c], stored bf16 row-major (o,c)
__global__ __launch_bounds__(256) void kW2(const float* oute_w, const float* Mfull, u16* Gb) {
  int gid = blockIdx.x * 256 + threadIdx.x;
  int o = gid >> 7, c = gid & 127;
  float s = 0;
  for (int k = 0; k < 128; ++k)
    s += oute_w[o * 128 + k] * Mfull[k * 128 + c];
  Gb[o * 128 + c] = f2b(s);
}

// ---------------------------------------------------------------------------
// N1: per 4 node-rows: npj, dpj, node_wh, srow, scol
// ---------------------------------------------------------------------------
__global__ __launch_bounds__(256) void kN1(const float* node, const float* diff,
                                           const float* Wn_w, const float* Wn_b,
                                           const float* Wd_w, const float* Wd_b,
                                           const float* Wh_w, const float* Wh_b,
                                           const float* attn, const float* sconst,
                                           float* npj_g, float* nwh_g,
                                           float* srow_g, float* scol_g) {
  __shared__ float nrow[4 * 512], npjl[4 * 512], drow[4 * 128], dpjl[4 * 128];
  const int t = threadIdx.x;
  const int r0 = blockIdx.x * 4;
  *(f32x4*)&nrow[t * 8]     = *(const f32x4*)(node + (size_t)r0 * 512 + t * 8);
  *(f32x4*)&nrow[t * 8 + 4] = *(const f32x4*)(node + (size_t)r0 * 512 + t * 8 + 4);
  if (t < 64) {
    *(f32x4*)&drow[t * 8]     = *(const f32x4*)(diff + (size_t)r0 * 128 + t * 8);
    *(f32x4*)&drow[t * 8 + 4] = *(const f32x4*)(diff + (size_t)r0 * 128 + t * 8 + 4);
  }
  __syncthreads();
  gemm_rows4<512, 512, 4>(nrow, Wn_w, Wn_b, npjl, npj_g + (size_t)r0 * 512, 512);
  gemm_rows4<128, 128, 4>(drow, Wd_w, Wd_b, dpjl, nullptr, 0);
  __syncthreads();
  {
    int d = t & 63, hh = t >> 6;
#pragma unroll
    for (int hi = 0; hi < 2; ++hi) {
      int h = hh + hi * 4;
      float wb = Wh_b[d];
      float acc[4] = {wb, wb, wb, wb};
      for (int k = 0; k < 64; ++k) {
        float w = Wh_w[d * 64 + k];
#pragma unroll
        for (int r = 0; r < 4; ++r) acc[r] += npjl[r * 512 + h * 64 + k] * w;
      }
#pragma unroll
      for (int r = 0; r < 4; ++r) nwh_g[(size_t)(r0 + r) * 512 + h * 64 + d] = acc[r];
    }
  }
  if (t < 32) {
    int r = t >> 3, h = t & 7;
    float shi = 0, shj = 0, sdi = 0, sdj = 0;
    for (int d = 0; d < 64; ++d) {
      float x = npjl[r * 512 + h * 64 + d];
      shi += x * attn[d];
      shj += x * attn[64 + d];
    }
    for (int e = 0; e < 16; ++e) {
      float x = dpjl[r * 128 + h * 16 + e];
      sdi += x * attn[144 + e];
      sdj += x * attn[160 + e];
    }
    srow_g[(r0 + r) * 8 + h] = shi + sdi + sconst[h];
    scol_g[(r0 + r) * 8 + h] = shj + sdj;
  }
}

// ---------------------------------------------------------------------------
// A: per block: 4 l-rows. scores (coalesced f32 dots) -> softmax -> P bf16 LDS
//    -> agg with nwh read ONCE for 4 l (4x reuse) -> nnp.
// ---------------------------------------------------------------------------
__global__ __launch_bounds__(256) void kA(const float* edge, const float* npj, const float* nwh,
                                          const float* srow, const float* scol,
                                          const float* vf, float* nnp) {
  __shared__ float sm[4608];            // scores [512][9]  / agg partials [2][4][512]
  __shared__ u16 Pb[4][512][8];         // bf16 unnormalized probs
  __shared__ float red[256];
  __shared__ float mxh8[8];
  __shared__ float inv8v[4][8];
  const int blk = blockIdx.x;
  const int b = blk >> 7, lt = blk & 127;
  const int t = threadIdx.x;
  const int sub = t & 15, rg = t >> 4;
  const int h = t & 7, seg = t >> 3;

  // preload score vectors for this lane's 8 columns
  f32x4 vrx[16];
#pragma unroll
  for (int q = 0; q < 16; ++q) vrx[q] = *(const f32x4*)(vf + sub * 64 + q * 4);

  for (int li = 0; li < 4; ++li) {
    const int l = lt * 4 + li;
    const size_t bl = (size_t)b * 512 + l;
    // ---- phase S ----
    const float* ebase = edge + (bl * 512 + rg) * 128 + sub * 8;
    f32x4 a0v, a1v, b0v, b1v;
    a0v = *(const f32x4*)ebase;             a1v = *(const f32x4*)(ebase + 4);
    b0v = *(const f32x4*)(ebase + 2048);    b1v = *(const f32x4*)(ebase + 2052);
#define SCORE_ROW(C0, C1, IT)                                                  \
    {                                                                          \
      float acc[8];                                                            \
      _Pragma("unroll") for (int h2 = 0; h2 < 8; ++h2) acc[h2] = 0.0f;         \
      _Pragma("unroll") for (int j = 0; j < 4; ++j) {                          \
        _Pragma("unroll") for (int h2 = 0; h2 < 8; ++h2) {                     \
          acc[h2] += C0[j] * vrx[j * 2 + (h2 >> 2)][h2 & 3];                   \
          acc[h2] += C1[j] * vrx[8 + j * 2 + (h2 >> 2)][h2 & 3];               \
        }                                                                      \
      }                                                                        \
      _Pragma("unroll") for (int d = 1; d < 16; d <<= 1) {                     \
        _Pragma("unroll") for (int h2 = 0; h2 < 8; ++h2)                       \
          acc[h2] += __shfl_xor(acc[h2], d, 64);                               \
      }                                                                        \
      if (sub < 8) {                                                           \
        float a = acc[0];                                                      \
        _Pragma("unroll") for (int h2 = 1; h2 < 8; ++h2)                       \
          if (sub == h2) a = acc[h2];                                          \
        sm[(IT * 16 + rg) * 9 + sub] = a;                                      \
      }                                                                        \
    }
    for (int it = 0; it < 32; it += 2) {
      SCORE_ROW(a0v, a1v, it);
      if (it + 2 < 32) {
        const float* p = ebase + (size_t)(it + 2) * 2048;
        a0v = *(const f32x4*)p; a1v = *(const f32x4*)(p + 4);
      }
      SCORE_ROW(b0v, b1v, (it + 1));
      if (it + 3 < 32) {
        const float* p = ebase + (size_t)(it + 3) * 2048;
        b0v = *(const f32x4*)p; b1v = *(const f32x4*)(p + 4);
      }
    }
#undef SCORE_ROW
    __syncthreads();
    // ---- softmax pass 1: bias+lrelu+diag, max ----
    const float srh2 = srow[bl * 8 + h];
    float mx = -__builtin_inff();
#pragma unroll 4
    for (int i = 0; i < 16; ++i) {
      int m = seg * 16 + i;
      float sv = sm[m * 9 + h] + srh2 + scol[((size_t)b * 512 + m) * 8 + h];
      sv = (m == l) ? -__builtin_inff() : (sv >= 0.0f ? sv : LRS * sv);
      sm[m * 9 + h] = sv;
      mx = fmaxf(mx, sv);
    }
    red[t] = mx;
    __syncthreads();
    if (t < 8) {
      float m2 = -__builtin_inff();
      for (int sg = 0; sg < 32; ++sg) m2 = fmaxf(m2, red[sg * 8 + t]);
      mxh8[t] = m2;
    }
    __syncthreads();
    // ---- softmax pass 2: exp, store P bf16, sum ----
    float mh = mxh8[h];
    float smv = 0;
#pragma unroll 4
    for (int i = 0; i < 16; ++i) {
      int m = seg * 16 + i;
      float p = __expf(sm[m * 9 + h] - mh);
      Pb[li][m][h] = f2b(p);
      smv += p;
    }
    red[t] = smv;
    __syncthreads();
    if (t < 8) {
      float s2 = 0;
      for (int sg = 0; sg < 32; ++sg) s2 += red[sg * 8 + t];
      inv8v[li][t] = 1.0f / s2;
    }
    __syncthreads();
  }

  // ---- agg: acc[li][o4] = sum_m P[li][m][h]*nwh[b,m,o4], m split in halves ----
  const int half = t >> 7, oq = t & 127;
  const int o4 = oq * 4, hh = oq >> 4;
  f32x4 acc[4] = {};
  const float* nb = nwh + (size_t)b * 512 * 512;
  for (int m = half * 256; m < half * 256 + 256; ++m) {
    f32x4 nv = *(const f32x4*)(nb + (size_t)m * 512 + o4);
#pragma unroll
    for (int li = 0; li < 4; ++li)
      acc[li] += bf2f(Pb[li][m][hh]) * nv;
  }
#pragma unroll
  for (int li = 0; li < 4; ++li)
    *(f32x4*)&sm[(half * 4 + li) * 512 + o4] = acc[li];
  __syncthreads();
  if (t < 128) {
    int ob = t * 4, h2 = t >> 4;
#pragma unroll
    for (int li = 0; li < 4; ++li) {
      f32x4 s0 = *(f32x4*)&sm[li * 512 + ob];
      f32x4 s1 = *(f32x4*)&sm[(4 + li) * 512 + ob];
      const size_t bl = (size_t)b * 512 + lt * 4 + li;
      f32x4 np4 = *(const f32x4*)(npj + bl * 512 + ob);
      float iv = inv8v[li][h2];
      f32x4 o;
#pragma unroll
      for (int j = 0; j < 4; ++j) {
        float a = (s0[j] + s1[j]) * iv;
        a = a >= 0.0f ? a : LRS * a;
        o[j] = np4[j] + a;
      }
      *(f32x4*)(nnp + bl * 512 + ob) = o;
    }
  }
}

// N2: new_node = nnp @ outn^T + b  -> f32 out (also serves as stage-2 input)
__global__ __launch_bounds__(256) void kN2(const float* nnp, const float* outn_w, const float* outn_b,
                                           float* out0) {
  __shared__ float xr[4 * 512];
  const int t = threadIdx.x;
  const int r0 = blockIdx.x * 4;
  *(f32x4*)&xr[t * 4]        = *(const f32x4*)(nnp + (size_t)r0 * 512 + t * 4);
  *(f32x4*)&xr[1024 + t * 4] = *(const f32x4*)(nnp + (size_t)r0 * 512 + 1024 + t * 4);
  __syncthreads();
  gemm_rows4<512, 512, 4>(xr, outn_w, outn_b, nullptr, out0 + (size_t)r0 * 512, 512);
}

// N34: np2, dp2 -> Rl/Rm (LDS) -> Pl/Pm = R @ oute^T (+bias on Pl side)
__global__ __launch_bounds__(256) void kN34(const float* nn, const float* diff,
                                            const float* Wn2_w, const float* Wn2_b,
                                            const float* Wd2_w, const float* Wd2_b,
                                            const float* edge_w, const float* cbe,
                                            const float* oute_w, const float* oute_b,
                                            float* Pl, float* Pm) {
  __shared__ float xr[4 * 512], np2l[4 * 512], dr[4 * 128], dp2l[4 * 128];
  __shared__ float Rls[4 * 128], Rms[4 * 128];
  const int t = threadIdx.x;
  const int r0 = blockIdx.x * 4;
  *(f32x4*)&xr[t * 4]        = *(const f32x4*)(nn + (size_t)r0 * 512 + t * 4);
  *(f32x4*)&xr[1024 + t * 4] = *(const f32x4*)(nn + (size_t)r0 * 512 + 1024 + t * 4);
  if (t < 64) {
    *(f32x4*)&dr[t * 8]     = *(const f32x4*)(diff + (size_t)r0 * 128 + t * 8);
    *(f32x4*)&dr[t * 8 + 4] = *(const f32x4*)(diff + (size_t)r0 * 128 + t * 8 + 4);
  }
  __syncthreads();
  gemm_rows4<512, 512, 4>(xr, Wn2_w, Wn2_b, np2l, nullptr, 0);
  gemm_rows4<128, 128, 4>(dr, Wd2_w, Wd2_b, dp2l, nullptr, 0);
  __syncthreads();
  {
    int hf = t & 127, which = t >> 7;
    int h = hf >> 4, fo = hf & 15;
    const float* wh = edge_w + fo * 176 + 16 + which * 64;   // W_hi / W_hj
    const float* wd = edge_w + fo * 176 + 144 + which * 16;  // W_di / W_dj
    float add = which ? 0.0f : cbe[hf];
    float* dst = which ? Rms : Rls;
#pragma unroll
    for (int r = 0; r < 4; ++r) {
      float a = add;
      for (int d = 0; d < 64; ++d) a += np2l[r * 512 + h * 64 + d] * wh[d];
      for (int e = 0; e < 16; ++e) a += dp2l[r * 128 + h * 16 + e] * wd[e];
      dst[r * 128 + hf] = a;
    }
  }
  __syncthreads();
  gemm_rows4<128, 128, 4>(Rls, oute_w, oute_b, nullptr, Pl + (size_t)r0 * 128, 128);
  gemm_rows4<128, 128, 4>(Rms, oute_w, nullptr, nullptr, Pm + (size_t)r0 * 128, 128);
}

// ---------------------------------------------------------------------------
// E: one-shot per 128-row tile; 64-row sub-tiles; Gt staged once.
// LDS 48KB -> 3 blocks/CU. new_edge = edge@G^T + Pl + Pm
// ---------------------------------------------------------------------------
__global__ __launch_bounds__(256) void kE(const float* edge, const u16* Gb,
                                          const float* Pl, const float* Pm, float* oute) {
  __shared__ u16 Gt[16384];   // 32 KB
  __shared__ u16 At[8192];    // 16 KB: 64 rows x 128 cols bf16, swizzled
  const int tile = blockIdx.x;
  const int bl = tile >> 2;
  const int b = bl >> 9;
  const int q0 = (tile & 3) * 128;
  const int t = threadIdx.x, lane = t & 63, w = t >> 6;
  // stage G once (coalesced)
#pragma unroll
  for (int i2 = 0; i2 < 8; ++i2) {
    int u = i2 * 256 + t;
    int row = u >> 4, cu = u & 15;
    *(u16x8*)(Gt + (row * 16 + (cu ^ (row & 7))) * 8) = *(const u16x8*)(Gb + u * 8);
  }
  const int wr = w >> 1, wc = w & 1;
  const int colL = lane & 15, kg = lane >> 4;
  const float* plp = Pl + (size_t)bl * 128;
  float plv[4];
#pragma unroll
  for (int n = 0; n < 4; ++n) plv[n] = plp[wc * 64 + n * 16 + colL];
  const int arow = t >> 2, aseg = t & 3;

  for (int sub = 0; sub < 2; ++sub) {
    const int r0 = q0 + sub * 64;
    // stage A sub-tile: 64 rows x 128 f32 -> bf16 swizzled
    {
      const float* p = edge + ((size_t)bl * 512 + r0 + arow) * 128 + aseg * 32;
      f32x4 v[8];
#pragma unroll
      for (int q = 0; q < 8; ++q) v[q] = *(const f32x4*)(p + q * 4);
#pragma unroll
      for (int jj = 0; jj < 4; ++jj) {
        u16x8 a8;
#pragma unroll
        for (int j2 = 0; j2 < 4; ++j2) {
          a8[j2]     = f2b(v[2 * jj][j2]);
          a8[4 + j2] = f2b(v[2 * jj + 1][j2]);
        }
        int cu = aseg * 4 + jj;
        *(u16x8*)(At + (arow * 16 + (cu ^ (arow & 7))) * 8) = a8;
      }
    }
    __syncthreads();
    f32x4 acc[2][4] = {};
#pragma unroll
    for (int ks = 0; ks < 4; ++ks) {
      int cu = ks * 4 + kg;
      bf16x8 af[2], bfv[4];
#pragma unroll
      for (int i = 0; i < 2; ++i) {
        int row = wr * 32 + i * 16 + colL;
        af[i] = *(bf16x8*)(At + (row * 16 + (cu ^ (row & 7))) * 8);
      }
#pragma unroll
      for (int n = 0; n < 4; ++n) {
        int orow = wc * 64 + n * 16 + colL;
        bfv[n] = *(bf16x8*)(Gt + (orow * 16 + (cu ^ (orow & 7))) * 8);
      }
#pragma unroll
      for (int i = 0; i < 2; ++i)
#pragma unroll
        for (int n = 0; n < 4; ++n)
          acc[i][n] = __builtin_amdgcn_mfma_f32_16x16x32_bf16(af[i], bfv[n], acc[i][n], 0, 0, 0);
    }
    // epilogue
    float* ob = oute + ((size_t)bl * 512 + r0) * 128;
#pragma unroll
    for (int i = 0; i < 2; ++i) {
#pragma unroll
      for (int r = 0; r < 4; ++r) {
        int m = wr * 32 + i * 16 + kg * 4 + r;
        const float* pmp = Pm + ((size_t)b * 512 + r0 + m) * 128;
#pragma unroll
        for (int n = 0; n < 4; ++n) {
          int o = wc * 64 + n * 16 + colL;
          ob[(size_t)m * 128 + o] = acc[i][n][r] + plv[n] + pmp[o];
        }
      }
    }
    __syncthreads();
  }
}

extern "C" void kernel_launch(void* const* d_in, const int* in_sizes, int n_in,
                              void* d_out, int out_size, void* d_ws, size_t ws_size,
                              hipStream_t stream) {
  (void)in_sizes; (void)n_in; (void)out_size; (void)ws_size;
  const float* node   = (const float*)d_in[0];
  const float* edge   = (const float*)d_in[1];
  const float* diff   = (const float*)d_in[2];
  const float* Wn_w   = (const float*)d_in[3];
  const float* Wn_b   = (const float*)d_in[4];
  const float* We_w   = (const float*)d_in[5];
  const float* We_b   = (const float*)d_in[6];
  const float* Wd_w   = (const float*)d_in[7];
  const float* Wd_b   = (const float*)d_in[8];
  const float* Wh_w   = (const float*)d_in[9];
  const float* Wh_b   = (const float*)d_in[10];
  const float* attn   = (const float*)d_in[11];
  const float* outn_w = (const float*)d_in[12];
  const float* outn_b = (const float*)d_in[13];
  const float* Wn2_w  = (const float*)d_in[14];
  const float* Wn2_b  = (const float*)d_in[15];
  const float* We2_w  = (const float*)d_in[16];
  const float* We2_b  = (const float*)d_in[17];
  const float* Wd2_w  = (const float*)d_in[18];
  const float* Wd2_b  = (const float*)d_in[19];
  const float* edge_w = (const float*)d_in[20];
  const float* edge_b = (const float*)d_in[21];
  const float* oute_w = (const float*)d_in[22];
  const float* oute_b = (const float*)d_in[23];

  float* out0 = (float*)d_out;           // new_node f32 (524288)
  float* out1 = out0 + 524288;           // new_edge f32

  float* f = (float*)d_ws;
  size_t off = 0;
  auto alloc = [&](size_t n) { float* p = f + off; off += (n + 7) & ~(size_t)7; return p; };
  float* npj    = alloc(524288);
  float* nwh    = alloc(524288);
  float* srow   = alloc(8192);
  float* scol   = alloc(8192);
  float* sconst = alloc(8);
  float* cbe    = alloc(128);
  float* Mfull  = alloc(16384);
  float* nnp    = alloc(524288);
  float* Pl     = alloc(131072);
  float* Pm     = alloc(131072);
  float* vf     = alloc(1024);
  u16* Gb = (u16*)(f + off); off += 8192;   // 16384 u16

  hipLaunchKernelGGL(kW1, dim3(73), dim3(256), 0, stream,
                     We_w, We_b, attn, We2_w, We2_b, edge_w, edge_b, Mfull, vf, cbe, sconst);
  hipLaunchKernelGGL(kW2, dim3(64), dim3(256), 0, stream, oute_w, Mfull, Gb);
  hipLaunchKernelGGL(kN1, dim3(256), dim3(256), 0, stream,
                     node, diff, Wn_w, Wn_b, Wd_w, Wd_b, Wh_w, Wh_b, attn, sconst,
                     npj, nwh, srow, scol);
  hipLaunchKernelGGL(kA, dim3(256), dim3(256), 0, stream,
                     edge, npj, nwh, srow, scol, vf, nnp);
  hipLaunchKernelGGL(kN2, dim3(256), dim3(256), 0, stream, nnp, outn_w, outn_b, out0);
  hipLaunchKernelGGL(kN34, dim3(256), dim3(256), 0, stream,
                     out0, diff, Wn2_w, Wn2_b, Wd2_w, Wd2_b, edge_w, cbe, oute_w, oute_b, Pl, Pm);
  hipLaunchKernelGGL(kE, dim3(4096), dim3(256), 0, stream, edge, Gb, Pl, Pm, out1);
}

// Round 6
// 458.675 us; speedup vs baseline: 1.0771x; 1.0306x over previous
//
#include <hip/hip_runtime.h>
#include <hip/hip_bf16.h>

typedef unsigned short u16;
typedef unsigned short u16x8 __attribute__((ext_vector_type(8)));
typedef __bf16 bf16x8 __attribute__((ext_vector_type(8)));
typedef float f32x4 __attribute__((ext_vector_type(4)));

#define LRS 0.2f

__device__ __forceinline__ u16 f2b(float f) {
  __hip_bfloat16 h = __float2bfloat16(f);
  return __builtin_bit_cast(u16, h);
}

// ---------------------------------------------------------------------------
// R rows (LDS f32, stride K) x W[O][K] f32 -> y[R][O]; KSEG lanes per K.
// ---------------------------------------------------------------------------
template<int K, int O, int KSEG, int R>
__device__ __forceinline__ void gemm_rowsR(const float* xr, const float* W, const float* bias,
                                           float* yl, float* yg, int ygstride) {
  constexpr int KPT = K / KSEG;
  constexpr int OPP = 256 / KSEG;
  const int t = threadIdx.x;
  const int ks = t % KSEG;
  const int oi = t / KSEG;
#pragma unroll
  for (int pass = 0; pass < O / OPP; ++pass) {
    const int o = pass * OPP + oi;
    float a[R];
#pragma unroll
    for (int r = 0; r < R; ++r) a[r] = 0.0f;
    const float* wp = W + (size_t)o * K + ks * KPT;
    const float* xb = xr + ks * KPT;
#pragma unroll 4
    for (int kc = 0; kc < KPT; kc += 4) {
      f32x4 w4 = *(const f32x4*)(wp + kc);
#pragma unroll
      for (int r = 0; r < R; ++r) {
        f32x4 x = *(const f32x4*)(xb + r * K + kc);
#pragma unroll
        for (int j = 0; j < 4; ++j) a[r] += x[j] * w4[j];
      }
    }
#pragma unroll
    for (int d = 1; d < KSEG; d <<= 1)
#pragma unroll
      for (int r = 0; r < R; ++r) a[r] += __shfl_xor(a[r], d, 64);
    if (ks == 0) {
      float bv = bias ? bias[o] : 0.0f;
#pragma unroll
      for (int r = 0; r < R; ++r) {
        float v = a[r] + bv;
        if (yl) yl[r * O + o] = v;
        if (yg) yg[(size_t)r * ygstride + o] = v;
      }
    }
  }
}

// ---------------------------------------------------------------------------
// W1: fold weights. Mfull[hf][c], vf[c][h] f32 (score vectors), cbe, sconst
// ---------------------------------------------------------------------------
__global__ __launch_bounds__(256) void kW1(const float* We_w, const float* We_b, const float* attn,
                                           const float* We2_w, const float* We2_b,
                                           const float* edge_w, const float* edge_b,
                                           float* Mfull, float* vf, float* cbe, float* sconst) {
  int gid = blockIdx.x * 256 + threadIdx.x;
  if (gid < 16384) {
    int hf = gid >> 7, c = gid & 127;
    int h = hf >> 4, fo = hf & 15;
    float s = 0;
    for (int e = 0; e < 16; ++e)
      s += edge_w[fo * 176 + e] * We2_w[(h * 16 + e) * 128 + c];
    Mfull[hf * 128 + c] = s;
  } else if (gid < 16384 + 2048) {
    int idx = gid - 16384;
    int c = idx >> 4, hc = idx & 15;
    if (hc < 8) {
      float s = 0;
      for (int e = 0; e < 16; ++e)
        s += We_w[(hc * 16 + e) * 128 + c] * attn[128 + e];
      vf[c * 8 + hc] = s;
    }
  } else if (gid < 18432 + 128) {
    int hf = gid - 18432;
    int h = hf >> 4, fo = hf & 15;
    float s = edge_b[fo];
    for (int e = 0; e < 16; ++e)
      s += We2_b[h * 16 + e] * edge_w[fo * 176 + e];
    cbe[hf] = s;
  } else if (gid < 18560 + 8) {
    int h = gid - 18560;
    float s = 0;
    for (int e = 0; e < 16; ++e)
      s += We_b[h * 16 + e] * attn[128 + e];
    sconst[h] = s;
  }
}

// W2: G[o][c] = sum_k oute_w[o,k]*Mfull[k][c], stored bf16 row-major (o,c)
__global__ __launch_bounds__(256) void kW2(const float* oute_w, const float* Mfull, u16* Gb) {
  int gid = blockIdx.x * 256 + threadIdx.x;
  int o = gid >> 7, c = gid & 127;
  float s = 0;
  for (int k = 0; k < 128; ++k)
    s += oute_w[o * 128 + k] * Mfull[k * 128 + c];
  Gb[o * 128 + c] = f2b(s);
}

// ---------------------------------------------------------------------------
// N1: per 2 node-rows (grid 512): npj, dpj, node_wh, srow, scol
// ---------------------------------------------------------------------------
__global__ __launch_bounds__(256) void kN1(const float* node, const float* diff,
                                           const float* Wn_w, const float* Wn_b,
                                           const float* Wd_w, const float* Wd_b,
                                           const float* Wh_w, const float* Wh_b,
                                           const float* attn, const float* sconst,
                                           float* npj_g, float* nwh_g,
                                           float* srow_g, float* scol_g) {
  __shared__ float nrow[2 * 512], npjl[2 * 512], drow[2 * 128], dpjl[2 * 128];
  const int t = threadIdx.x;
  const int r0 = blockIdx.x * 2;
  *(f32x4*)&nrow[t * 4] = *(const f32x4*)(node + (size_t)r0 * 512 + t * 4);
  if (t < 64) *(f32x4*)&drow[t * 4] = *(const f32x4*)(diff + (size_t)r0 * 128 + t * 4);
  __syncthreads();
  gemm_rowsR<512, 512, 4, 2>(nrow, Wn_w, Wn_b, npjl, npj_g + (size_t)r0 * 512, 512);
  gemm_rowsR<128, 128, 4, 2>(drow, Wd_w, Wd_b, dpjl, nullptr, 0);
  __syncthreads();
  {
    int d = t & 63, hh = t >> 6;
#pragma unroll
    for (int hi = 0; hi < 2; ++hi) {
      int h = hh + hi * 4;
      float wb = Wh_b[d];
      float acc[2] = {wb, wb};
      for (int k = 0; k < 64; ++k) {
        float w = Wh_w[d * 64 + k];
#pragma unroll
        for (int r = 0; r < 2; ++r) acc[r] += npjl[r * 512 + h * 64 + k] * w;
      }
#pragma unroll
      for (int r = 0; r < 2; ++r) nwh_g[(size_t)(r0 + r) * 512 + h * 64 + d] = acc[r];
    }
  }
  if (t < 16) {
    int r = t >> 3, h = t & 7;
    float shi = 0, shj = 0, sdi = 0, sdj = 0;
    for (int d = 0; d < 64; ++d) {
      float x = npjl[r * 512 + h * 64 + d];
      shi += x * attn[d];
      shj += x * attn[64 + d];
    }
    for (int e = 0; e < 16; ++e) {
      float x = dpjl[r * 128 + h * 16 + e];
      sdi += x * attn[144 + e];
      sdj += x * attn[160 + e];
    }
    srow_g[(r0 + r) * 8 + h] = shi + sdi + sconst[h];
    scol_g[(r0 + r) * 8 + h] = shj + sdj;
  }
}

// ---------------------------------------------------------------------------
// A: per (b,l) block (grid 1024): coalesced score dots -> softmax -> agg -> nnp
// ---------------------------------------------------------------------------
__global__ __launch_bounds__(256) void kA(const float* edge, const float* npj, const float* nwh,
                                          const float* srow, const float* scol,
                                          const float* vf, float* nnp) {
  __shared__ float sm[4608];            // scores [512][9]
  __shared__ float part[2][512];
  __shared__ float red[256];
  __shared__ float mxh8[8], inv8[8];
  const int bl = blockIdx.x;
  const int b = bl >> 9, l = bl & 511;
  const int t = threadIdx.x;
  const int sub = t & 15, rg = t >> 4;
  const int h = t & 7, seg = t >> 3;

  f32x4 vrx[16];
#pragma unroll
  for (int q = 0; q < 16; ++q) vrx[q] = *(const f32x4*)(vf + sub * 64 + q * 4);

  // ---- phase S: se[m][h] = edge[bl,m,:]·v[:,h] ----
  {
    const float* ebase = edge + ((size_t)bl * 512 + rg) * 128 + sub * 8;
    f32x4 a0v, a1v, b0v, b1v;
    a0v = *(const f32x4*)ebase;          a1v = *(const f32x4*)(ebase + 4);
    b0v = *(const f32x4*)(ebase + 2048); b1v = *(const f32x4*)(ebase + 2052);
#define SCORE_ROW(C0, C1, IT)                                                  \
    {                                                                          \
      float acc[8];                                                            \
      _Pragma("unroll") for (int h2 = 0; h2 < 8; ++h2) acc[h2] = 0.0f;         \
      _Pragma("unroll") for (int j = 0; j < 4; ++j) {                          \
        _Pragma("unroll") for (int h2 = 0; h2 < 8; ++h2) {                     \
          acc[h2] += C0[j] * vrx[j * 2 + (h2 >> 2)][h2 & 3];                   \
          acc[h2] += C1[j] * vrx[8 + j * 2 + (h2 >> 2)][h2 & 3];               \
        }                                                                      \
      }                                                                        \
      _Pragma("unroll") for (int d = 1; d < 16; d <<= 1) {                     \
        _Pragma("unroll") for (int h2 = 0; h2 < 8; ++h2)                       \
          acc[h2] += __shfl_xor(acc[h2], d, 64);                               \
      }                                                                        \
      if (sub < 8) {                                                           \
        float a = acc[0];                                                      \
        _Pragma("unroll") for (int h2 = 1; h2 < 8; ++h2)                       \
          if (sub == h2) a = acc[h2];                                          \
        sm[(IT * 16 + rg) * 9 + sub] = a;                                      \
      }                                                                        \
    }
    for (int it = 0; it < 32; it += 2) {
      SCORE_ROW(a0v, a1v, it);
      if (it + 2 < 32) {
        const float* p = ebase + (size_t)(it + 2) * 2048;
        a0v = *(const f32x4*)p; a1v = *(const f32x4*)(p + 4);
      }
      SCORE_ROW(b0v, b1v, (it + 1));
      if (it + 3 < 32) {
        const float* p = ebase + (size_t)(it + 3) * 2048;
        b0v = *(const f32x4*)p; b1v = *(const f32x4*)(p + 4);
      }
    }
#undef SCORE_ROW
  }
  __syncthreads();
  // ---- softmax pass 1 ----
  const float srh2 = srow[(size_t)bl * 8 + h];
  float mx = -__builtin_inff();
#pragma unroll 4
  for (int i = 0; i < 16; ++i) {
    int m = seg * 16 + i;
    float sv = sm[m * 9 + h] + srh2 + scol[((size_t)b * 512 + m) * 8 + h];
    sv = (m == l) ? -__builtin_inff() : (sv >= 0.0f ? sv : LRS * sv);
    sm[m * 9 + h] = sv;
    mx = fmaxf(mx, sv);
  }
  red[t] = mx;
  __syncthreads();
  if (t < 8) {
    float m2 = -__builtin_inff();
    for (int sg = 0; sg < 32; ++sg) m2 = fmaxf(m2, red[sg * 8 + t]);
    mxh8[t] = m2;
  }
  __syncthreads();
  float mh = mxh8[h];
  float smv = 0;
#pragma unroll 4
  for (int i = 0; i < 16; ++i) {
    int m = seg * 16 + i;
    float p = __expf(sm[m * 9 + h] - mh);
    sm[m * 9 + h] = p;
    smv += p;
  }
  red[t] = smv;
  __syncthreads();
  if (t < 8) {
    float s2 = 0;
    for (int sg = 0; sg < 32; ++sg) s2 += red[sg * 8 + t];
    inv8[t] = 1.0f / s2;
  }
  __syncthreads();
  // ---- agg ----
  const int half = t >> 7, oq = t & 127;
  const int o4 = oq * 4, hh = oq >> 4;
  f32x4 acc4a = {0, 0, 0, 0}, acc4b = {0, 0, 0, 0};
  const float* nb = nwh + (size_t)b * 512 * 512;
  for (int m = half * 256; m < half * 256 + 256; m += 2) {
    acc4a += sm[m * 9 + hh]       * *(const f32x4*)(nb + (size_t)m * 512 + o4);
    acc4b += sm[(m + 1) * 9 + hh] * *(const f32x4*)(nb + (size_t)(m + 1) * 512 + o4);
  }
  *(f32x4*)&part[half][o4] = acc4a + acc4b;
  __syncthreads();
  if (t < 128) {
    int ob = t * 4, h2 = t >> 4;
    f32x4 s0 = *(f32x4*)&part[0][ob];
    f32x4 s1 = *(f32x4*)&part[1][ob];
    f32x4 np4 = *(const f32x4*)(npj + (size_t)bl * 512 + ob);
    float iv = inv8[h2];
    f32x4 o;
#pragma unroll
    for (int j = 0; j < 4; ++j) {
      float a = (s0[j] + s1[j]) * iv;
      a = a >= 0.0f ? a : LRS * a;
      o[j] = np4[j] + a;
    }
    *(f32x4*)(nnp + (size_t)bl * 512 + ob) = o;
  }
}

// ---------------------------------------------------------------------------
// N234 (fused, 2 rows/block, grid 512): nnp -> out0 -> np2/dp2 -> R -> Pl/Pm
// ---------------------------------------------------------------------------
__global__ __launch_bounds__(256) void kN234(const float* nnp, const float* diff,
                                             const float* outn_w, const float* outn_b,
                                             const float* Wn2_w, const float* Wn2_b,
                                             const float* Wd2_w, const float* Wd2_b,
                                             const float* edge_w, const float* cbe,
                                             const float* oute_w, const float* oute_b,
                                             float* out0, float* Pl, float* Pm) {
  __shared__ float xr[2 * 512], o0l[2 * 512], np2l[2 * 512], dr[2 * 128], dp2l[2 * 128];
  __shared__ float Rls[2 * 128], Rms[2 * 128];
  const int t = threadIdx.x;
  const int r0 = blockIdx.x * 2;
  *(f32x4*)&xr[t * 4] = *(const f32x4*)(nnp + (size_t)r0 * 512 + t * 4);
  if (t < 64) *(f32x4*)&dr[t * 4] = *(const f32x4*)(diff + (size_t)r0 * 128 + t * 4);
  __syncthreads();
  gemm_rowsR<512, 512, 4, 2>(xr, outn_w, outn_b, o0l, out0 + (size_t)r0 * 512, 512);
  gemm_rowsR<128, 128, 4, 2>(dr, Wd2_w, Wd2_b, dp2l, nullptr, 0);
  __syncthreads();
  gemm_rowsR<512, 512, 4, 2>(o0l, Wn2_w, Wn2_b, np2l, nullptr, 0);
  __syncthreads();
  {
    int hf = t & 127, which = t >> 7;
    int h = hf >> 4, fo = hf & 15;
    const float* wh = edge_w + fo * 176 + 16 + which * 64;   // W_hi / W_hj
    const float* wd = edge_w + fo * 176 + 144 + which * 16;  // W_di / W_dj
    float add = which ? 0.0f : cbe[hf];
    float* dst = which ? Rms : Rls;
#pragma unroll
    for (int r = 0; r < 2; ++r) {
      float a = add;
      for (int d = 0; d < 64; ++d) a += np2l[r * 512 + h * 64 + d] * wh[d];
      for (int e = 0; e < 16; ++e) a += dp2l[r * 128 + h * 16 + e] * wd[e];
      dst[r * 128 + hf] = a;
    }
  }
  __syncthreads();
  gemm_rowsR<128, 128, 4, 2>(Rls, oute_w, oute_b, nullptr, Pl + (size_t)r0 * 128, 128);
  gemm_rowsR<128, 128, 4, 2>(Rms, oute_w, nullptr, nullptr, Pm + (size_t)r0 * 128, 128);
}

// ---------------------------------------------------------------------------
// E: per 128-row tile (grid 4096); swapped MFMA operands -> f32x4 stores.
// new_edge = edge@G^T + Pl + Pm
// ---------------------------------------------------------------------------
__global__ __launch_bounds__(256) void kE(const float* edge, const u16* Gb,
                                          const float* Pl, const float* Pm, float* oute) {
  __shared__ u16 Gt[16384];   // 32 KB
  __shared__ u16 At[8192];    // 16 KB
  const int tile = blockIdx.x;
  const int bl = tile >> 2;
  const int b = bl >> 9;
  const int q0 = (tile & 3) * 128;
  const int t = threadIdx.x, lane = t & 63, w = t >> 6;
#pragma unroll
  for (int i2 = 0; i2 < 8; ++i2) {
    int u = i2 * 256 + t;
    int row = u >> 4, cu = u & 15;
    *(u16x8*)(Gt + (row * 16 + (cu ^ (row & 7))) * 8) = *(const u16x8*)(Gb + u * 8);
  }
  const int wr = w >> 1, wc = w & 1;
  const int colL = lane & 15, kg = lane >> 4;
  const float* plp = Pl + (size_t)bl * 128;
  f32x4 plv4[4];
#pragma unroll
  for (int n = 0; n < 4; ++n) plv4[n] = *(const f32x4*)(plp + wc * 64 + n * 16 + kg * 4);
  const int arow = t >> 2, aseg = t & 3;

  for (int sub = 0; sub < 2; ++sub) {
    const int r0 = q0 + sub * 64;
    {
      const float* p = edge + ((size_t)bl * 512 + r0 + arow) * 128 + aseg * 32;
      f32x4 v[8];
#pragma unroll
      for (int q = 0; q < 8; ++q) v[q] = *(const f32x4*)(p + q * 4);
#pragma unroll
      for (int jj = 0; jj < 4; ++jj) {
        u16x8 a8;
#pragma unroll
        for (int j2 = 0; j2 < 4; ++j2) {
          a8[j2]     = f2b(v[2 * jj][j2]);
          a8[4 + j2] = f2b(v[2 * jj + 1][j2]);
        }
        int cu = aseg * 4 + jj;
        *(u16x8*)(At + (arow * 16 + (cu ^ (arow & 7))) * 8) = a8;
      }
    }
    __syncthreads();
    f32x4 acc[2][4] = {};
#pragma unroll
    for (int ks = 0; ks < 4; ++ks) {
      int cu = ks * 4 + kg;
      bf16x8 af[2], bfv[4];
#pragma unroll
      for (int i = 0; i < 2; ++i) {
        int row = wr * 32 + i * 16 + colL;
        af[i] = *(bf16x8*)(At + (row * 16 + (cu ^ (row & 7))) * 8);
      }
#pragma unroll
      for (int n = 0; n < 4; ++n) {
        int orow = wc * 64 + n * 16 + colL;
        bfv[n] = *(bf16x8*)(Gt + (orow * 16 + (cu ^ (orow & 7))) * 8);
      }
#pragma unroll
      for (int i = 0; i < 2; ++i)
#pragma unroll
        for (int n = 0; n < 4; ++n)
          acc[i][n] = __builtin_amdgcn_mfma_f32_16x16x32_bf16(bfv[n], af[i], acc[i][n], 0, 0, 0);
    }
    // epilogue: D col(lane&15)=m-row, reg r = o offset -> f32x4 stores
    float* ob = oute + ((size_t)bl * 512 + r0) * 128;
#pragma unroll
    for (int i = 0; i < 2; ++i) {
      int m = wr * 32 + i * 16 + colL;
      const float* pmp = Pm + ((size_t)b * 512 + r0 + m) * 128;
      float* orow = ob + (size_t)m * 128;
#pragma unroll
      for (int n = 0; n < 4; ++n) {
        int oc = wc * 64 + n * 16 + kg * 4;
        f32x4 pm4 = *(const f32x4*)(pmp + oc);
        f32x4 o4;
#pragma unroll
        for (int r = 0; r < 4; ++r) o4[r] = acc[i][n][r] + plv4[n][r] + pm4[r];
        *(f32x4*)(orow + oc) = o4;
      }
    }
    __syncthreads();
  }
}

extern "C" void kernel_launch(void* const* d_in, const int* in_sizes, int n_in,
                              void* d_out, int out_size, void* d_ws, size_t ws_size,
                              hipStream_t stream) {
  (void)in_sizes; (void)n_in; (void)out_size; (void)ws_size;
  const float* node   = (const float*)d_in[0];
  const float* edge   = (const float*)d_in[1];
  const float* diff   = (const float*)d_in[2];
  const float* Wn_w   = (const float*)d_in[3];
  const float* Wn_b   = (const float*)d_in[4];
  const float* We_w   = (const float*)d_in[5];
  const float* We_b   = (const float*)d_in[6];
  const float* Wd_w   = (const float*)d_in[7];
  const float* Wd_b   = (const float*)d_in[8];
  const float* Wh_w   = (const float*)d_in[9];
  const float* Wh_b   = (const float*)d_in[10];
  const float* attn   = (const float*)d_in[11];
  const float* outn_w = (const float*)d_in[12];
  const float* outn_b = (const float*)d_in[13];
  const float* Wn2_w  = (const float*)d_in[14];
  const float* Wn2_b  = (const float*)d_in[15];
  const float* We2_w  = (const float*)d_in[16];
  const float* We2_b  = (const float*)d_in[17];
  const float* Wd2_w  = (const float*)d_in[18];
  const float* Wd2_b  = (const float*)d_in[19];
  const float* edge_w = (const float*)d_in[20];
  const float* edge_b = (const float*)d_in[21];
  const float* oute_w = (const float*)d_in[22];
  const float* oute_b = (const float*)d_in[23];

  float* out0 = (float*)d_out;           // new_node f32 (524288)
  float* out1 = out0 + 524288;           // new_edge f32

  float* f = (float*)d_ws;
  size_t off = 0;
  auto alloc = [&](size_t n) { float* p = f + off; off += (n + 7) & ~(size_t)7; return p; };
  float* npj    = alloc(524288);
  float* nwh    = alloc(524288);
  float* srow   = alloc(8192);
  float* scol   = alloc(8192);
  float* sconst = alloc(8);
  float* cbe    = alloc(128);
  float* Mfull  = alloc(16384);
  float* nnp    = alloc(524288);
  float* Pl     = alloc(131072);
  float* Pm     = alloc(131072);
  float* vf     = alloc(1024);
  u16* Gb = (u16*)(f + off); off += 8192;

  hipLaunchKernelGGL(kW1, dim3(73), dim3(256), 0, stream,
                     We_w, We_b, attn, We2_w, We2_b, edge_w, edge_b, Mfull, vf, cbe, sconst);
  hipLaunchKernelGGL(kW2, dim3(64), dim3(256), 0, stream, oute_w, Mfull, Gb);
  hipLaunchKernelGGL(kN1, dim3(512), dim3(256), 0, stream,
                     node, diff, Wn_w, Wn_b, Wd_w, Wd_b, Wh_w, Wh_b, attn, sconst,
                     npj, nwh, srow, scol);
  hipLaunchKernelGGL(kA, dim3(1024), dim3(256), 0, stream,
                     edge, npj, nwh, srow, scol, vf, nnp);
  hipLaunchKernelGGL(kN234, dim3(512), dim3(256), 0, stream,
                     nnp, diff, outn_w, outn_b, Wn2_w, Wn2_b, Wd2_w, Wd2_b,
                     edge_w, cbe, oute_w, oute_b, out0, Pl, Pm);
  hipLaunchKernelGGL(kE, dim3(4096), dim3(256), 0, stream, edge, Gb, Pl, Pm, out1);
}